// Round 1
// baseline (3449.638 us; speedup 1.0000x reference)
//
#include <hip/hip_runtime.h>
#include <hip/hip_bf16.h>
#include <math.h>

// Problem dims (fixed)
#define BT    4096     // B*T rows
#define TSEQ  2048
#define DMODEL 1024
#define EDIM  2048
#define E2    4096     // 2*E
#define GG    16       // groups
#define NS    16       // state
#define DFF   4096

// ---------------- RMSNorm ----------------
__global__ void rmsnorm_kernel(const float* __restrict__ x, const float* __restrict__ w,
                               float* __restrict__ out) {
  int row = blockIdx.x;
  const float* xr = x + (size_t)row * DMODEL;
  float ss = 0.f;
#pragma unroll
  for (int i = 0; i < 4; ++i) {
    float v = xr[threadIdx.x + i * 256];
    ss += v * v;
  }
#pragma unroll
  for (int off = 32; off; off >>= 1) ss += __shfl_down(ss, off, 64);
  __shared__ float wsum[4];
  int lane = threadIdx.x & 63, wid = threadIdx.x >> 6;
  if (lane == 0) wsum[wid] = ss;
  __syncthreads();
  __shared__ float s_rms;
  if (threadIdx.x == 0)
    s_rms = rsqrtf((wsum[0] + wsum[1] + wsum[2] + wsum[3]) * (1.0f / DMODEL) + 1e-6f);
  __syncthreads();
  float rms = s_rms;
  float* orow = out + (size_t)row * DMODEL;
#pragma unroll
  for (int i = 0; i < 4; ++i) {
    int c = threadIdx.x + i * 256;
    orow[c] = xr[c] * rms * w[c];
  }
}

// ---------------- fp32 tiled GEMM: C[M,N] = A[M,K] @ W[K,N] (+res) ----------------
#define BM 64
#define BN 64
#define BKK 16

__global__ __launch_bounds__(256) void gemm_f32(
    const float* __restrict__ A, const float* __restrict__ W,
    const float* __restrict__ res, float* __restrict__ C,
    int M, int N, int K) {
  __shared__ float As[BKK][BM + 1];
  __shared__ float Bs[BKK][BN];
  int tid = threadIdx.x;
  int tx = tid & 15, ty = tid >> 4;
  int row0 = blockIdx.y * BM, col0 = blockIdx.x * BN;
  int am = tid >> 2, ak = (tid & 3) << 2;
  int bk = tid >> 4, bn = (tid & 15) << 2;
  float acc[4][4] = {};
  const float* Aptr = A + (size_t)(row0 + am) * K + ak;
  const float* Wptr = W + (size_t)bk * N + col0 + bn;
  for (int k0 = 0; k0 < K; k0 += BKK) {
    float4 av = *(const float4*)(Aptr + k0);
    float4 bv = *(const float4*)(Wptr + (size_t)k0 * N);
    __syncthreads();
    As[ak + 0][am] = av.x;
    As[ak + 1][am] = av.y;
    As[ak + 2][am] = av.z;
    As[ak + 3][am] = av.w;
    *(float4*)&Bs[bk][bn] = bv;
    __syncthreads();
#pragma unroll
    for (int k = 0; k < BKK; ++k) {
      float a_[4], b_[4];
#pragma unroll
      for (int i = 0; i < 4; ++i) a_[i] = As[k][(ty << 2) + i];
#pragma unroll
      for (int j = 0; j < 4; ++j) b_[j] = Bs[k][(tx << 2) + j];
#pragma unroll
      for (int i = 0; i < 4; ++i)
#pragma unroll
        for (int j = 0; j < 4; ++j)
          acc[i][j] = fmaf(a_[i], b_[j], acc[i][j]);
    }
  }
#pragma unroll
  for (int i = 0; i < 4; ++i) {
    size_t r = (size_t)(row0 + (ty << 2) + i);
    float* crow = C + r * N + col0 + (tx << 2);
    float4 o = make_float4(acc[i][0], acc[i][1], acc[i][2], acc[i][3]);
    if (res) {
      const float4 rv = *(const float4*)(res + r * N + col0 + (tx << 2));
      o.x += rv.x; o.y += rv.y; o.z += rv.z; o.w += rv.w;
    }
    *(float4*)crow = o;
  }
}

// ---------------- depthwise causal conv (K=7) ----------------
__global__ void dwconv_kernel(const float* __restrict__ uv, const float* __restrict__ cw,
                              float* __restrict__ vout) {
  int e = blockIdx.x * 256 + threadIdx.x;   // 0..2047
  int bt = blockIdx.y;                       // 0..4095
  int t = bt & (TSEQ - 1);
  float w[7];
#pragma unroll
  for (int k = 0; k < 7; ++k) w[k] = cw[e * 7 + k];
  const float* col = uv + (size_t)bt * E2 + EDIM + e;  // v half, row bt
  float acc = 0.f;
#pragma unroll
  for (int k = 0; k < 7; ++k) {
    int ts = t - 6 + k;
    if (ts >= 0) acc += w[k] * col[(ts - t) * (int)E2];
  }
  vout[(size_t)bt * EDIM + e] = acc;
}

// ---------------- dt projection + softplus ----------------
__global__ void dtproj_kernel(const float* __restrict__ v, const float* __restrict__ w,
                              const float* __restrict__ bias, float* __restrict__ dtout) {
  int row = blockIdx.x;
  const float* vr = v + (size_t)row * EDIM;
  float acc[GG] = {};
  for (int e = threadIdx.x; e < EDIM; e += 256) {
    float vv = vr[e];
    const float* wr = w + (size_t)e * GG;
#pragma unroll
    for (int g = 0; g < GG; ++g) acc[g] = fmaf(vv, wr[g], acc[g]);
  }
#pragma unroll
  for (int g = 0; g < GG; ++g)
#pragma unroll
    for (int off = 32; off; off >>= 1) acc[g] += __shfl_down(acc[g], off, 64);
  __shared__ float red[4][GG];
  int lane = threadIdx.x & 63, wid = threadIdx.x >> 6;
  if (lane == 0) {
#pragma unroll
    for (int g = 0; g < GG; ++g) red[wid][g] = acc[g];
  }
  __syncthreads();
  if (threadIdx.x < GG) {
    float s = red[0][threadIdx.x] + red[1][threadIdx.x] + red[2][threadIdx.x] +
              red[3][threadIdx.x] + bias[threadIdx.x];
    dtout[(size_t)row * GG + threadIdx.x] = (s > 20.f) ? s : log1pf(expf(s));
  }
}

// ---------------- sequential selective scan ----------------
__global__ void scan_kernel(const float* __restrict__ Bt, const float* __restrict__ Ct,
                            const float* __restrict__ dt, const float* __restrict__ A_log,
                            float* __restrict__ y) {
  int tid = threadIdx.x;                // 512 threads: (b,g,n)
  int b = tid >> 8, g = (tid >> 4) & 15, n = tid & 15;
  float A = -expf(A_log[g * NS + n]);
  float state = 0.f;
  const size_t bcOff = (size_t)b * TSEQ * 256 + (size_t)g * NS + n;
  const size_t dtOff = (size_t)b * TSEQ * GG + g;
  float Bv = Bt[bcOff], Cv = Ct[bcOff], dv = dt[dtOff];
  for (int t = 0; t < TSEQ; ++t) {
    float nB = 0.f, nC = 0.f, nd = 0.f;
    if (t < TSEQ - 1) {
      size_t r = bcOff + (size_t)(t + 1) * 256;
      nB = Bt[r];
      nC = Ct[r];
      nd = dt[dtOff + (size_t)(t + 1) * GG];
    }
    float ab = expf(dv * A);
    state = ab * state + dv * Bv;
    float p = state * Cv;
#pragma unroll
    for (int off = 8; off; off >>= 1) p += __shfl_down(p, off, 16);
    if (n == 0) y[(size_t)(b * TSEQ + t) * GG + g] = p;
    Bv = nB; Cv = nC; dv = nd;
  }
}

// ---------------- gating: yg = sigmoid(u) * y_broadcast ----------------
__global__ void gate_kernel(const float* __restrict__ uv, const float* __restrict__ y,
                            float* __restrict__ yg) {
  size_t idx = (size_t)blockIdx.x * 256 + threadIdx.x;  // over BT*EDIM
  int bt = (int)(idx >> 11);
  int e = (int)(idx & (EDIM - 1));
  float u = uv[(size_t)bt * E2 + e];
  float yv = y[(size_t)bt * GG + (e >> 7)];
  yg[idx] = yv * (1.f / (1.f + expf(-u)));
}

// ---------------- swiglu: t1 = silu(t1) * t3 ----------------
__global__ void swiglu_kernel(float* __restrict__ t1, const float* __restrict__ t3) {
  size_t idx = (size_t)blockIdx.x * 256 + threadIdx.x;  // over BT*DFF
  float g = t1[idx];
  float s = g * (1.f / (1.f + expf(-g)));
  t1[idx] = s * t3[idx];
}

extern "C" void kernel_launch(void* const* d_in, const int* in_sizes, int n_in,
                              void* d_out, int out_size, void* d_ws, size_t ws_size,
                              hipStream_t stream) {
  (void)in_sizes; (void)n_in; (void)out_size; (void)ws_size;
  const float* x         = (const float*)d_in[0];
  const float* norm1_w   = (const float*)d_in[1];
  const float* in_proj_w = (const float*)d_in[2];
  const float* conv_w    = (const float*)d_in[3];
  const float* B_proj_w  = (const float*)d_in[4];
  const float* C_proj_w  = (const float*)d_in[5];
  const float* dt_proj_w = (const float*)d_in[6];
  const float* dt_proj_b = (const float*)d_in[7];
  const float* A_log     = (const float*)d_in[8];
  const float* out_proj_w= (const float*)d_in[9];
  const float* norm2_w   = (const float*)d_in[10];
  const float* w1        = (const float*)d_in[11];
  const float* w2        = (const float*)d_in[12];
  const float* w3        = (const float*)d_in[13];
  float* out = (float*)d_out;

  char* ws = (char*)d_ws;
  float* uv  = (float*)(ws + 0);          // BT*E2    = 64 MiB  (later reused as t1)
  float* h   = (float*)(ws + 67108864);   // BT*D     = 16 MiB
  float* v   = (float*)(ws + 83886080);   // BT*E     = 32 MiB  (later reused as yg)
  float* Btb = (float*)(ws + 117440512);  // BT*256   = 4 MiB
  float* Ctb = (float*)(ws + 121634816);  // BT*256   = 4 MiB
  float* dtb = (float*)(ws + 125829120);  // BT*16
  float* yb  = (float*)(ws + 126091264);  // BT*16
  float* t3  = (float*)(ws + 126353408);  // BT*DFF   = 64 MiB

  // 1) h = rmsnorm(x, norm1_w)
  rmsnorm_kernel<<<BT, 256, 0, stream>>>(x, norm1_w, h);
  // 2) uv = h @ in_proj_w  [BT, 2E]
  gemm_f32<<<dim3(E2 / BN, BT / BM), 256, 0, stream>>>(h, in_proj_w, nullptr, uv, BT, E2, DMODEL);
  // 3) v = causal dwconv(uv[:, E:2E])
  dwconv_kernel<<<dim3(EDIM / 256, BT), 256, 0, stream>>>(uv, conv_w, v);
  // 4) Bt = v @ B_proj_w ; Ct = v @ C_proj_w
  gemm_f32<<<dim3(256 / BN, BT / BM), 256, 0, stream>>>(v, B_proj_w, nullptr, Btb, BT, 256, EDIM);
  gemm_f32<<<dim3(256 / BN, BT / BM), 256, 0, stream>>>(v, C_proj_w, nullptr, Ctb, BT, 256, EDIM);
  // 5) dt = softplus(v @ dt_proj_w + b)
  dtproj_kernel<<<BT, 256, 0, stream>>>(v, dt_proj_w, dt_proj_b, dtb);
  // 6) sequential scan -> y [BT, G]
  scan_kernel<<<1, 512, 0, stream>>>(Btb, Ctb, dtb, A_log, yb);
  // 7) yg = sigmoid(u) * broadcast(y)   (reuse v buffer)
  gate_kernel<<<(BT * EDIM) / 256, 256, 0, stream>>>(uv, yb, v);
  // 8) out = yg @ out_proj_w + x   (residual 1)
  gemm_f32<<<dim3(DMODEL / BN, BT / BM), 256, 0, stream>>>(v, out_proj_w, x, out, BT, DMODEL, EDIM);
  // 9) h = rmsnorm(out, norm2_w)
  rmsnorm_kernel<<<BT, 256, 0, stream>>>(out, norm2_w, h);
  // 10) t1 = h @ w1 (reuse uv) ; t3 = h @ w3
  gemm_f32<<<dim3(DFF / BN, BT / BM), 256, 0, stream>>>(h, w1, nullptr, uv, BT, DFF, DMODEL);
  gemm_f32<<<dim3(DFF / BN, BT / BM), 256, 0, stream>>>(h, w3, nullptr, t3, BT, DFF, DMODEL);
  // 11) t1 = silu(t1) * t3
  swiglu_kernel<<<(BT * DFF) / 256, 256, 0, stream>>>(uv, t3);
  // 12) out = t1 @ w2 + out   (residual 2)
  gemm_f32<<<dim3(DMODEL / BN, BT / BM), 256, 0, stream>>>(uv, w2, out, out, BT, DMODEL, DFF);
}

// Round 2
// 575.264 us; speedup vs baseline: 5.9966x; 5.9966x over previous
//
#include <hip/hip_runtime.h>
#include <hip/hip_bf16.h>
#include <math.h>

// Problem dims (fixed)
#define BT    4096     // B*T rows
#define TSEQ  2048
#define DMODEL 1024
#define EDIM  2048
#define E2    4096     // 2*E
#define GG    16       // groups
#define NS    16       // state
#define DFF   4096
#define NCH   64       // scan chunks
#define CL    32       // chunk length (NCH*CL == TSEQ)

typedef __attribute__((ext_vector_type(8))) short short8_t;
typedef __attribute__((ext_vector_type(4))) float f32x4;

__device__ __forceinline__ void gload_lds16(const void* g, void* l) {
  __builtin_amdgcn_global_load_lds((const __attribute__((address_space(1))) void*)g,
                                   (__attribute__((address_space(3))) void*)l, 16, 0, 0);
}

// ---------------- RMSNorm (fp32 in -> bf16 out) ----------------
__global__ void rmsnorm_bf16(const float* __restrict__ x, const float* __restrict__ w,
                             __hip_bfloat16* __restrict__ out) {
  int row = blockIdx.x;
  const float* xr = x + (size_t)row * DMODEL;
  float ss = 0.f;
#pragma unroll
  for (int i = 0; i < 4; ++i) {
    float v = xr[threadIdx.x + i * 256];
    ss += v * v;
  }
#pragma unroll
  for (int off = 32; off; off >>= 1) ss += __shfl_down(ss, off, 64);
  __shared__ float wsum[4];
  int lane = threadIdx.x & 63, wid = threadIdx.x >> 6;
  if (lane == 0) wsum[wid] = ss;
  __syncthreads();
  __shared__ float s_rms;
  if (threadIdx.x == 0)
    s_rms = rsqrtf((wsum[0] + wsum[1] + wsum[2] + wsum[3]) * (1.0f / DMODEL) + 1e-6f);
  __syncthreads();
  float rms = s_rms;
  __hip_bfloat16* orow = out + (size_t)row * DMODEL;
#pragma unroll
  for (int i = 0; i < 4; ++i) {
    int c = threadIdx.x + i * 256;
    orow[c] = __float2bfloat16(xr[c] * rms * w[c]);
  }
}

// ---------------- transpose + fp32->bf16 convert: W[K,N] -> WT[N,K] ----------------
__global__ void transpose_to_bf16(const float* __restrict__ W, __hip_bfloat16* __restrict__ WT,
                                  int K, int N) {
  __shared__ float tile[32][33];
  int tx = threadIdx.x & 31, ty = threadIdx.x >> 5;  // 32 x 8
  int n0 = blockIdx.x * 32, k0 = blockIdx.y * 32;
#pragma unroll
  for (int i = 0; i < 4; ++i)
    tile[ty + i * 8][tx] = W[(size_t)(k0 + ty + i * 8) * N + n0 + tx];
  __syncthreads();
#pragma unroll
  for (int i = 0; i < 4; ++i)
    WT[(size_t)(n0 + ty + i * 8) * K + k0 + tx] = __float2bfloat16(tile[tx][ty + i * 8]);
}

// ---------------- bf16 MFMA GEMM: C[M,N] = A[M,K] @ WT[N,K]^T (+res) ----------------
// A row-major bf16 [M,K]; WT row-major bf16 [N,K]. 128x128 tile, BK=64,
// 4 waves (2x2), each wave 64x64 via 4x4 fragments of 16x16x32.
template <int OUT_BF16>
__global__ __launch_bounds__(256) void gemm_mfma(
    const __hip_bfloat16* __restrict__ A, const __hip_bfloat16* __restrict__ WT,
    const float* __restrict__ res, void* __restrict__ Cout, int M, int N, int K) {
  __shared__ __hip_bfloat16 As[128][64];
  __shared__ __hip_bfloat16 Bs[128][64];
  int tid = threadIdx.x;
  int lane = tid & 63, wid = tid >> 6;
  int wr = wid >> 1, wc = wid & 1;
  int brow = blockIdx.y * 128, bcol = blockIdx.x * 128;
  int lr = lane & 15, lq = lane >> 4;

  f32x4 acc[4][4];
#pragma unroll
  for (int m = 0; m < 4; ++m)
#pragma unroll
    for (int n = 0; n < 4; ++n) acc[m][n] = (f32x4){0.f, 0.f, 0.f, 0.f};

  const char* Ab = (const char*)(A + (size_t)brow * K);
  const char* Bb = (const char*)(WT + (size_t)bcol * K);
  const size_t rowBytes = (size_t)K * 2;

  for (int k0 = 0; k0 < K; k0 += 64) {
    __syncthreads();
    // stage A tile: 128 rows x 64 cols bf16 = 16KB -> 1024 16B chunks
#pragma unroll
    for (int i = 0; i < 4; ++i) {
      int blk = i * 4 + wid;                  // 0..15, wave-uniform
      int o16 = (blk << 6) + lane;            // chunk index 0..1023
      int r = o16 >> 3, cb = (o16 & 7) << 4;  // row, byte-col within 128B row
      gload_lds16(Ab + (size_t)r * rowBytes + (size_t)k0 * 2 + cb,
                  (char*)&As[0][0] + ((size_t)blk << 10));
    }
#pragma unroll
    for (int i = 0; i < 4; ++i) {
      int blk = i * 4 + wid;
      int o16 = (blk << 6) + lane;
      int r = o16 >> 3, cb = (o16 & 7) << 4;
      gload_lds16(Bb + (size_t)r * rowBytes + (size_t)k0 * 2 + cb,
                  (char*)&Bs[0][0] + ((size_t)blk << 10));
    }
    __syncthreads();  // drains vmcnt + barrier

#pragma unroll
    for (int kk = 0; kk < 64; kk += 32) {
      short8_t a[4], b[4];
#pragma unroll
      for (int m = 0; m < 4; ++m)
        a[m] = *(const short8_t*)&As[wr * 64 + m * 16 + lr][kk + lq * 8];
#pragma unroll
      for (int n = 0; n < 4; ++n)
        b[n] = *(const short8_t*)&Bs[wc * 64 + n * 16 + lr][kk + lq * 8];
#pragma unroll
      for (int m = 0; m < 4; ++m)
#pragma unroll
        for (int n = 0; n < 4; ++n)
          acc[m][n] = __builtin_amdgcn_mfma_f32_16x16x32_bf16(a[m], b[n], acc[m][n], 0, 0, 0);
    }
  }

  // epilogue: C/D layout col=lane&15, row=(lane>>4)*4+reg
#pragma unroll
  for (int m = 0; m < 4; ++m) {
    int row0 = brow + wr * 64 + m * 16 + lq * 4;
#pragma unroll
    for (int n = 0; n < 4; ++n) {
      int col = bcol + wc * 64 + n * 16 + lr;
#pragma unroll
      for (int j = 0; j < 4; ++j) {
        size_t idx = (size_t)(row0 + j) * N + col;
        float o = acc[m][n][j];
        if (res) o += res[idx];
        if constexpr (OUT_BF16)
          ((__hip_bfloat16*)Cout)[idx] = __float2bfloat16(o);
        else
          ((float*)Cout)[idx] = o;
      }
    }
  }
}

// ---------------- depthwise causal conv (K=7), bf16 in/out ----------------
__global__ void dwconv_bf16(const __hip_bfloat16* __restrict__ uvb, const float* __restrict__ cw,
                            __hip_bfloat16* __restrict__ vout) {
  int e = blockIdx.x * 256 + threadIdx.x;   // 0..2047
  int bt = blockIdx.y;                       // 0..4095
  int t = bt & (TSEQ - 1);
  float w[7];
#pragma unroll
  for (int k = 0; k < 7; ++k) w[k] = cw[e * 7 + k];
  const __hip_bfloat16* col = uvb + (size_t)bt * E2 + EDIM + e;  // v half
  float acc = 0.f;
#pragma unroll
  for (int k = 0; k < 7; ++k) {
    int ts = t - 6 + k;
    if (ts >= 0) acc += w[k] * __bfloat162float(col[(ts - t) * (int)E2]);
  }
  vout[(size_t)bt * EDIM + e] = __float2bfloat16(acc);
}

// ---------------- dt projection + softplus (bf16 v, fp32 weights) ----------------
__global__ void dtproj_kernel(const __hip_bfloat16* __restrict__ v, const float* __restrict__ w,
                              const float* __restrict__ bias, float* __restrict__ dtout) {
  int row = blockIdx.x;
  const __hip_bfloat16* vr = v + (size_t)row * EDIM;
  float acc[GG] = {};
  for (int e = threadIdx.x; e < EDIM; e += 256) {
    float vv = __bfloat162float(vr[e]);
    const float* wr = w + (size_t)e * GG;
#pragma unroll
    for (int g = 0; g < GG; ++g) acc[g] = fmaf(vv, wr[g], acc[g]);
  }
#pragma unroll
  for (int g = 0; g < GG; ++g)
#pragma unroll
    for (int off = 32; off; off >>= 1) acc[g] += __shfl_down(acc[g], off, 64);
  __shared__ float red[4][GG];
  int lane = threadIdx.x & 63, wid = threadIdx.x >> 6;
  if (lane == 0) {
#pragma unroll
    for (int g = 0; g < GG; ++g) red[wid][g] = acc[g];
  }
  __syncthreads();
  if (threadIdx.x < GG) {
    float s = red[0][threadIdx.x] + red[1][threadIdx.x] + red[2][threadIdx.x] +
              red[3][threadIdx.x] + bias[threadIdx.x];
    dtout[(size_t)row * GG + threadIdx.x] = (s > 20.f) ? s : log1pf(expf(s));
  }
}

// ---------------- chunked selective scan ----------------
// Recurrence s_t = a_t*s_{t-1} + dt_t*B_t, a_t = exp(dt_t*A). 64 chunks of 32.
__global__ void scan_phase1(const float* __restrict__ Bt, const float* __restrict__ dt,
                            const float* __restrict__ A_log,
                            float* __restrict__ Pc, float* __restrict__ Sc) {
  int c = blockIdx.x, tid = threadIdx.x;
  int b = tid >> 8, g = (tid >> 4) & 15, n = tid & 15;
  float A = -expf(A_log[g * NS + n]);
  int t0 = c * CL;
  size_t bOff = (size_t)b * TSEQ * 256 + g * 16 + n;
  size_t dOff = (size_t)b * TSEQ * GG + g;
  float P = 1.f, S = 0.f;
  float Bv = Bt[bOff + (size_t)t0 * 256], dv = dt[dOff + (size_t)t0 * GG];
  for (int t = t0; t < t0 + CL; ++t) {
    float nB = 0.f, nd = 0.f;
    if (t + 1 < t0 + CL) {
      nB = Bt[bOff + (size_t)(t + 1) * 256];
      nd = dt[dOff + (size_t)(t + 1) * GG];
    }
    float a = expf(dv * A);
    S = a * S + dv * Bv;
    P *= a;
    Bv = nB; dv = nd;
  }
  Pc[c * 512 + tid] = P;
  Sc[c * 512 + tid] = S;
}

__global__ void scan_phase2(const float* __restrict__ Pc, const float* __restrict__ Sc,
                            float* __restrict__ Init) {
  int tid = threadIdx.x;
  float s = 0.f;
  for (int c = 0; c < NCH; ++c) {
    Init[c * 512 + tid] = s;
    s = Pc[c * 512 + tid] * s + Sc[c * 512 + tid];
  }
}

__global__ void scan_phase3(const float* __restrict__ Bt, const float* __restrict__ Ct,
                            const float* __restrict__ dt, const float* __restrict__ A_log,
                            const float* __restrict__ Init, float* __restrict__ y) {
  int c = blockIdx.x, tid = threadIdx.x;
  int b = tid >> 8, g = (tid >> 4) & 15, n = tid & 15;
  float A = -expf(A_log[g * NS + n]);
  int t0 = c * CL;
  size_t bOff = (size_t)b * TSEQ * 256 + g * 16 + n;
  size_t dOff = (size_t)b * TSEQ * GG + g;
  float state = Init[c * 512 + tid];
  float Bv = Bt[bOff + (size_t)t0 * 256], Cv = Ct[bOff + (size_t)t0 * 256],
        dv = dt[dOff + (size_t)t0 * GG];
  for (int t = t0; t < t0 + CL; ++t) {
    float nB = 0.f, nC = 0.f, nd = 0.f;
    if (t + 1 < t0 + CL) {
      size_t r = bOff + (size_t)(t + 1) * 256;
      nB = Bt[r]; nC = Ct[r];
      nd = dt[dOff + (size_t)(t + 1) * GG];
    }
    float a = expf(dv * A);
    state = a * state + dv * Bv;
    float p = state * Cv;
#pragma unroll
    for (int off = 8; off; off >>= 1) p += __shfl_down(p, off, 16);
    if (n == 0) y[(size_t)(b * TSEQ + t) * GG + g] = p;
    Bv = nB; Cv = nC; dv = nd;
  }
}

// ---------------- gating: yg = sigmoid(u) * y_broadcast (bf16 out) ----------------
__global__ void gate_bf16(const __hip_bfloat16* __restrict__ uvb, const float* __restrict__ y,
                          __hip_bfloat16* __restrict__ yg) {
  size_t idx = (size_t)blockIdx.x * 256 + threadIdx.x;  // over BT*EDIM
  int bt = (int)(idx >> 11);
  int e = (int)(idx & (EDIM - 1));
  float u = __bfloat162float(uvb[(size_t)bt * E2 + e]);
  float yv = y[(size_t)bt * GG + (e >> 7)];
  yg[idx] = __float2bfloat16(yv / (1.f + expf(-u)));
}

// ---------------- swiglu: ffb = silu(t1)*t3 (bf16) ----------------
__global__ void swiglu_bf16(const __hip_bfloat16* __restrict__ t1,
                            const __hip_bfloat16* __restrict__ t3,
                            __hip_bfloat16* __restrict__ ffb) {
  size_t idx = (size_t)blockIdx.x * 256 + threadIdx.x;  // over BT*DFF
  float g = __bfloat162float(t1[idx]);
  float s = g / (1.f + expf(-g));
  ffb[idx] = __float2bfloat16(s * __bfloat162float(t3[idx]));
}

extern "C" void kernel_launch(void* const* d_in, const int* in_sizes, int n_in,
                              void* d_out, int out_size, void* d_ws, size_t ws_size,
                              hipStream_t stream) {
  (void)in_sizes; (void)n_in; (void)out_size; (void)ws_size;
  const float* x         = (const float*)d_in[0];
  const float* norm1_w   = (const float*)d_in[1];
  const float* in_proj_w = (const float*)d_in[2];
  const float* conv_w    = (const float*)d_in[3];
  const float* B_proj_w  = (const float*)d_in[4];
  const float* C_proj_w  = (const float*)d_in[5];
  const float* dt_proj_w = (const float*)d_in[6];
  const float* dt_proj_b = (const float*)d_in[7];
  const float* A_log     = (const float*)d_in[8];
  const float* out_proj_w= (const float*)d_in[9];
  const float* norm2_w   = (const float*)d_in[10];
  const float* w1        = (const float*)d_in[11];
  const float* w2        = (const float*)d_in[12];
  const float* w3        = (const float*)d_in[13];
  float* out = (float*)d_out;

  char* ws = (char*)d_ws;
  const size_t MB = 1024 * 1024;
  __hip_bfloat16* uvb = (__hip_bfloat16*)(ws + 0);        // [4096,4096] 32MB; later t1b
  __hip_bfloat16* t3b = (__hip_bfloat16*)(ws + 32 * MB);  // [4096,4096] 32MB
  __hip_bfloat16* vb  = (__hip_bfloat16*)(ws + 64 * MB);  // [4096,2048] 16MB
  __hip_bfloat16* yg  = (__hip_bfloat16*)(ws + 80 * MB);  // [4096,2048] 16MB
  __hip_bfloat16* ffb = vb;                               // 32MB overlay (vb+yg dead)
  __hip_bfloat16* hb  = (__hip_bfloat16*)(ws + 96 * MB);  // [4096,1024] 8MB
  float* Btb  = (float*)(ws + 104 * MB);                  // [4096,256] 4MB
  float* Ctb  = (float*)(ws + 108 * MB);                  // 4MB
  float* dtb  = (float*)(ws + 112 * MB);                  // 256KB
  float* yb   = (float*)(ws + 112 * MB + 256 * 1024);     // 256KB
  float* Pc   = (float*)(ws + 113 * MB);                  // 128KB
  float* Sc   = (float*)(ws + 113 * MB + 128 * 1024);     // 128KB
  float* Init = (float*)(ws + 113 * MB + 256 * 1024);     // 128KB
  __hip_bfloat16* inT = (__hip_bfloat16*)(ws + 114 * MB); // [4096,1024] 8MB
  __hip_bfloat16* BpT = (__hip_bfloat16*)(ws + 122 * MB); // [256,2048] 1MB
  __hip_bfloat16* CpT = (__hip_bfloat16*)(ws + 123 * MB); // 1MB
  __hip_bfloat16* opT = (__hip_bfloat16*)(ws + 124 * MB); // [1024,2048] 4MB
  __hip_bfloat16* w1T = (__hip_bfloat16*)(ws + 128 * MB); // [4096,1024] 8MB
  __hip_bfloat16* w3T = (__hip_bfloat16*)(ws + 136 * MB); // 8MB
  __hip_bfloat16* w2T = (__hip_bfloat16*)(ws + 144 * MB); // [1024,4096] 8MB

  // 0) weight transpose+convert (W[K,N] -> WT[N,K] bf16)
  transpose_to_bf16<<<dim3(4096 / 32, 1024 / 32), 256, 0, stream>>>(in_proj_w, inT, 1024, 4096);
  transpose_to_bf16<<<dim3(256 / 32, 2048 / 32), 256, 0, stream>>>(B_proj_w, BpT, 2048, 256);
  transpose_to_bf16<<<dim3(256 / 32, 2048 / 32), 256, 0, stream>>>(C_proj_w, CpT, 2048, 256);
  transpose_to_bf16<<<dim3(1024 / 32, 2048 / 32), 256, 0, stream>>>(out_proj_w, opT, 2048, 1024);
  transpose_to_bf16<<<dim3(4096 / 32, 1024 / 32), 256, 0, stream>>>(w1, w1T, 1024, 4096);
  transpose_to_bf16<<<dim3(4096 / 32, 1024 / 32), 256, 0, stream>>>(w3, w3T, 1024, 4096);
  transpose_to_bf16<<<dim3(1024 / 32, 4096 / 32), 256, 0, stream>>>(w2, w2T, 4096, 1024);

  // 1) hb = rmsnorm(x) in bf16
  rmsnorm_bf16<<<BT, 256, 0, stream>>>(x, norm1_w, hb);
  // 2) uvb = hb @ in_proj  [4096,4096] bf16
  gemm_mfma<1><<<dim3(E2 / 128, BT / 128), 256, 0, stream>>>(hb, inT, nullptr, uvb, BT, E2, DMODEL);
  // 3) vb = causal dwconv(uvb[:, E:2E])
  dwconv_bf16<<<dim3(EDIM / 256, BT), 256, 0, stream>>>(uvb, conv_w, vb);
  // 4) Btb/Ctb = vb @ {B,C}_proj (fp32)
  gemm_mfma<0><<<dim3(256 / 128, BT / 128), 256, 0, stream>>>(vb, BpT, nullptr, Btb, BT, 256, EDIM);
  gemm_mfma<0><<<dim3(256 / 128, BT / 128), 256, 0, stream>>>(vb, CpT, nullptr, Ctb, BT, 256, EDIM);
  // 5) dtb = softplus(vb @ dt_proj + b)
  dtproj_kernel<<<BT, 256, 0, stream>>>(vb, dt_proj_w, dt_proj_b, dtb);
  // 6) chunked scan -> yb [BT, G]
  scan_phase1<<<NCH, 512, 0, stream>>>(Btb, dtb, A_log, Pc, Sc);
  scan_phase2<<<1, 512, 0, stream>>>(Pc, Sc, Init);
  scan_phase3<<<NCH, 512, 0, stream>>>(Btb, Ctb, dtb, A_log, Init, yb);
  // 7) yg = sigmoid(u) * broadcast(y)
  gate_bf16<<<(BT * EDIM) / 256, 256, 0, stream>>>(uvb, yb, yg);
  // 8) out = yg @ out_proj + x
  gemm_mfma<0><<<dim3(DMODEL / 128, BT / 128), 256, 0, stream>>>(yg, opT, x, out, BT, DMODEL, EDIM);
  // 9) hb = rmsnorm(out)
  rmsnorm_bf16<<<BT, 256, 0, stream>>>(out, norm2_w, hb);
  // 10) t1b(=uvb) = hb @ w1 ; t3b = hb @ w3 (bf16)
  gemm_mfma<1><<<dim3(DFF / 128, BT / 128), 256, 0, stream>>>(hb, w1T, nullptr, uvb, BT, DFF, DMODEL);
  gemm_mfma<1><<<dim3(DFF / 128, BT / 128), 256, 0, stream>>>(hb, w3T, nullptr, t3b, BT, DFF, DMODEL);
  // 11) ffb = silu(t1)*t3 (bf16, overlays vb/yg)
  swiglu_bf16<<<(BT * DFF) / 256, 256, 0, stream>>>(uvb, t3b, ffb);
  // 12) out += ffb @ w2
  gemm_mfma<0><<<dim3(DMODEL / 128, BT / 128), 256, 0, stream>>>(ffb, w2T, out, out, BT, DMODEL, DFF);
}

// Round 3
// 537.892 us; speedup vs baseline: 6.4133x; 1.0695x over previous
//
#include <hip/hip_runtime.h>
#include <hip/hip_bf16.h>
#include <math.h>

// Problem dims (fixed)
#define BT    4096     // B*T rows
#define TSEQ  2048
#define DMODEL 1024
#define EDIM  2048
#define E2    4096     // 2*E
#define GG    16       // groups
#define NS    16       // state
#define DFF   4096
#define NCH   64       // scan chunks
#define CL    32       // chunk length (NCH*CL == TSEQ)

typedef __attribute__((ext_vector_type(8))) short short8_t;
typedef __attribute__((ext_vector_type(4))) float f32x4;

__device__ __forceinline__ void gload_lds16(const void* g, void* l) {
  __builtin_amdgcn_global_load_lds((const __attribute__((address_space(1))) void*)g,
                                   (__attribute__((address_space(3))) void*)l, 16, 0, 0);
}

// ---------------- RMSNorm (fp32 in -> bf16 out) ----------------
__global__ void rmsnorm_bf16(const float* __restrict__ x, const float* __restrict__ w,
                             __hip_bfloat16* __restrict__ out) {
  int row = blockIdx.x;
  const float* xr = x + (size_t)row * DMODEL;
  float ss = 0.f;
#pragma unroll
  for (int i = 0; i < 4; ++i) {
    float v = xr[threadIdx.x + i * 256];
    ss += v * v;
  }
#pragma unroll
  for (int off = 32; off; off >>= 1) ss += __shfl_down(ss, off, 64);
  __shared__ float wsum[4];
  int lane = threadIdx.x & 63, wid = threadIdx.x >> 6;
  if (lane == 0) wsum[wid] = ss;
  __syncthreads();
  __shared__ float s_rms;
  if (threadIdx.x == 0)
    s_rms = rsqrtf((wsum[0] + wsum[1] + wsum[2] + wsum[3]) * (1.0f / DMODEL) + 1e-6f);
  __syncthreads();
  float rms = s_rms;
  __hip_bfloat16* orow = out + (size_t)row * DMODEL;
#pragma unroll
  for (int i = 0; i < 4; ++i) {
    int c = threadIdx.x + i * 256;
    orow[c] = __float2bfloat16(xr[c] * rms * w[c]);
  }
}

// ---------------- transpose + fp32->bf16 convert: W[K,N] -> WT[N,K] ----------------
__global__ void transpose_to_bf16(const float* __restrict__ W, __hip_bfloat16* __restrict__ WT,
                                  int K, int N) {
  __shared__ float tile[32][33];
  int tx = threadIdx.x & 31, ty = threadIdx.x >> 5;  // 32 x 8
  int n0 = blockIdx.x * 32, k0 = blockIdx.y * 32;
#pragma unroll
  for (int i = 0; i < 4; ++i)
    tile[ty + i * 8][tx] = W[(size_t)(k0 + ty + i * 8) * N + n0 + tx];
  __syncthreads();
#pragma unroll
  for (int i = 0; i < 4; ++i)
    WT[(size_t)(n0 + ty + i * 8) * K + k0 + tx] = __float2bfloat16(tile[tx][ty + i * 8]);
}

// ---------------- bf16 MFMA GEMM, double-buffered 2-phase (T3-min) ----------------
// C[M,N] = A[M,K] @ WT[N,K]^T (+res). 128x128 tile, BK=64, 4 waves 2x2,
// 4x4 fragments of 16x16x32. 1D grid with XCD swizzle (gridDim.x % 8 == 0).
template <int OUT_BF16>
__global__ __launch_bounds__(256) void gemm_mfma(
    const __hip_bfloat16* __restrict__ A, const __hip_bfloat16* __restrict__ WT,
    const float* __restrict__ res, void* __restrict__ Cout,
    int M, int N, int K, int nbx) {
  __shared__ __hip_bfloat16 As[2][128][64];
  __shared__ __hip_bfloat16 Bs[2][128][64];
  int tid = threadIdx.x;
  int lane = tid & 63, wid = tid >> 6;
  int wr = wid >> 1, wc = wid & 1;

  // XCD-aware swizzle (nwg multiple of 8)
  int nwg = gridDim.x;
  int q = nwg >> 3;
  int sw = (blockIdx.x & 7) * q + (blockIdx.x >> 3);
  int bx = sw % nbx, by = sw / nbx;
  int brow = by * 128, bcol = bx * 128;
  int lr = lane & 15, lq = lane >> 4;

  f32x4 acc[4][4];
#pragma unroll
  for (int m = 0; m < 4; ++m)
#pragma unroll
    for (int n = 0; n < 4; ++n) acc[m][n] = (f32x4){0.f, 0.f, 0.f, 0.f};

  const char* Ab = (const char*)(A + (size_t)brow * K);
  const char* Bb = (const char*)(WT + (size_t)bcol * K);
  const size_t rowBytes = (size_t)K * 2;

  // stage one K-tile (t) into buffer buf
  auto stage = [&](int buf, int t) {
    const size_t kb = (size_t)t * 128;  // t*64 cols * 2B
    char* asBase = (char*)&As[buf][0][0];
    char* bsBase = (char*)&Bs[buf][0][0];
#pragma unroll
    for (int i = 0; i < 4; ++i) {
      int blk = i * 4 + wid;
      int o16 = (blk << 6) + lane;
      int r = o16 >> 3, cb = (o16 & 7) << 4;
      gload_lds16(Ab + (size_t)r * rowBytes + kb + cb, asBase + (blk << 10));
    }
#pragma unroll
    for (int i = 0; i < 4; ++i) {
      int blk = i * 4 + wid;
      int o16 = (blk << 6) + lane;
      int r = o16 >> 3, cb = (o16 & 7) << 4;
      gload_lds16(Bb + (size_t)r * rowBytes + kb + cb, bsBase + (blk << 10));
    }
  };

  const int nt = K >> 6;
  // prologue
  stage(0, 0);
  __syncthreads();  // drains vmcnt, all waves see tile 0

  int cur = 0;
  for (int t = 0; t < nt; ++t) {
    if (t + 1 < nt) stage(cur ^ 1, t + 1);  // issue next-tile loads first
#pragma unroll
    for (int kk = 0; kk < 64; kk += 32) {
      short8_t a[4], b[4];
#pragma unroll
      for (int m = 0; m < 4; ++m)
        a[m] = *(const short8_t*)&As[cur][wr * 64 + m * 16 + lr][kk + lq * 8];
#pragma unroll
      for (int n = 0; n < 4; ++n)
        b[n] = *(const short8_t*)&Bs[cur][wc * 64 + n * 16 + lr][kk + lq * 8];
#pragma unroll
      for (int m = 0; m < 4; ++m)
#pragma unroll
        for (int n = 0; n < 4; ++n)
          acc[m][n] = __builtin_amdgcn_mfma_f32_16x16x32_bf16(a[m], b[n], acc[m][n], 0, 0, 0);
    }
    __syncthreads();  // drains staged loads (vmcnt 0) + barrier
    cur ^= 1;
  }

  // epilogue: C/D layout col=lane&15, row=(lane>>4)*4+reg
#pragma unroll
  for (int m = 0; m < 4; ++m) {
    int row0 = brow + wr * 64 + m * 16 + lq * 4;
#pragma unroll
    for (int n = 0; n < 4; ++n) {
      int col = bcol + wc * 64 + n * 16 + lr;
#pragma unroll
      for (int j = 0; j < 4; ++j) {
        size_t idx = (size_t)(row0 + j) * N + col;
        float o = acc[m][n][j];
        if (res) o += res[idx];
        if constexpr (OUT_BF16)
          ((__hip_bfloat16*)Cout)[idx] = __float2bfloat16(o);
        else
          ((float*)Cout)[idx] = o;
      }
    }
  }
}

// ---------------- depthwise causal conv (K=7), bf16 in/out ----------------
__global__ void dwconv_bf16(const __hip_bfloat16* __restrict__ uvb, const float* __restrict__ cw,
                            __hip_bfloat16* __restrict__ vout) {
  int e = blockIdx.x * 256 + threadIdx.x;   // 0..2047
  int bt = blockIdx.y;                       // 0..4095
  int t = bt & (TSEQ - 1);
  float w[7];
#pragma unroll
  for (int k = 0; k < 7; ++k) w[k] = cw[e * 7 + k];
  const __hip_bfloat16* col = uvb + (size_t)bt * E2 + EDIM + e;  // v half
  float acc = 0.f;
#pragma unroll
  for (int k = 0; k < 7; ++k) {
    int ts = t - 6 + k;
    if (ts >= 0) acc += w[k] * __bfloat162float(col[(ts - t) * (int)E2]);
  }
  vout[(size_t)bt * EDIM + e] = __float2bfloat16(acc);
}

// ---------------- dt projection + softplus (bf16 v, fp32 weights) ----------------
__global__ void dtproj_kernel(const __hip_bfloat16* __restrict__ v, const float* __restrict__ w,
                              const float* __restrict__ bias, float* __restrict__ dtout) {
  int row = blockIdx.x;
  const __hip_bfloat16* vr = v + (size_t)row * EDIM;
  float acc[GG] = {};
  for (int e = threadIdx.x; e < EDIM; e += 256) {
    float vv = __bfloat162float(vr[e]);
    const float* wr = w + (size_t)e * GG;
#pragma unroll
    for (int g = 0; g < GG; ++g) acc[g] = fmaf(vv, wr[g], acc[g]);
  }
#pragma unroll
  for (int g = 0; g < GG; ++g)
#pragma unroll
    for (int off = 32; off; off >>= 1) acc[g] += __shfl_down(acc[g], off, 64);
  __shared__ float red[4][GG];
  int lane = threadIdx.x & 63, wid = threadIdx.x >> 6;
  if (lane == 0) {
#pragma unroll
    for (int g = 0; g < GG; ++g) red[wid][g] = acc[g];
  }
  __syncthreads();
  if (threadIdx.x < GG) {
    float s = red[0][threadIdx.x] + red[1][threadIdx.x] + red[2][threadIdx.x] +
              red[3][threadIdx.x] + bias[threadIdx.x];
    dtout[(size_t)row * GG + threadIdx.x] = (s > 20.f) ? s : log1pf(expf(s));
  }
}

// ---------------- chunked selective scan (BC fused: [BT,512], Ct at +256) ----------------
__global__ void scan_phase1(const float* __restrict__ BC, const float* __restrict__ dt,
                            const float* __restrict__ A_log,
                            float* __restrict__ Pc, float* __restrict__ Sc) {
  int c = blockIdx.x, tid = threadIdx.x;
  int b = tid >> 8, g = (tid >> 4) & 15, n = tid & 15;
  float A = -expf(A_log[g * NS + n]);
  int t0 = c * CL;
  size_t bOff = (size_t)b * TSEQ * 512 + g * 16 + n;
  size_t dOff = (size_t)b * TSEQ * GG + g;
  float P = 1.f, S = 0.f;
  float Bv = BC[bOff + (size_t)t0 * 512], dv = dt[dOff + (size_t)t0 * GG];
  for (int t = t0; t < t0 + CL; ++t) {
    float nB = 0.f, nd = 0.f;
    if (t + 1 < t0 + CL) {
      nB = BC[bOff + (size_t)(t + 1) * 512];
      nd = dt[dOff + (size_t)(t + 1) * GG];
    }
    float a = expf(dv * A);
    S = a * S + dv * Bv;
    P *= a;
    Bv = nB; dv = nd;
  }
  Pc[c * 512 + tid] = P;
  Sc[c * 512 + tid] = S;
}

__global__ void scan_phase2(const float* __restrict__ Pc, const float* __restrict__ Sc,
                            float* __restrict__ Init) {
  int tid = threadIdx.x;
  float s = 0.f;
  for (int c = 0; c < NCH; ++c) {
    Init[c * 512 + tid] = s;
    s = Pc[c * 512 + tid] * s + Sc[c * 512 + tid];
  }
}

__global__ void scan_phase3(const float* __restrict__ BC, const float* __restrict__ dt,
                            const float* __restrict__ A_log, const float* __restrict__ Init,
                            float* __restrict__ y) {
  int c = blockIdx.x, tid = threadIdx.x;
  int b = tid >> 8, g = (tid >> 4) & 15, n = tid & 15;
  float A = -expf(A_log[g * NS + n]);
  int t0 = c * CL;
  size_t bOff = (size_t)b * TSEQ * 512 + g * 16 + n;
  size_t dOff = (size_t)b * TSEQ * GG + g;
  float state = Init[c * 512 + tid];
  float Bv = BC[bOff + (size_t)t0 * 512], Cv = BC[bOff + 256 + (size_t)t0 * 512],
        dv = dt[dOff + (size_t)t0 * GG];
  for (int t = t0; t < t0 + CL; ++t) {
    float nB = 0.f, nC = 0.f, nd = 0.f;
    if (t + 1 < t0 + CL) {
      size_t r = bOff + (size_t)(t + 1) * 512;
      nB = BC[r]; nC = BC[r + 256];
      nd = dt[dOff + (size_t)(t + 1) * GG];
    }
    float a = expf(dv * A);
    state = a * state + dv * Bv;
    float p = state * Cv;
#pragma unroll
    for (int off = 8; off; off >>= 1) p += __shfl_down(p, off, 16);
    if (n == 0) y[(size_t)(b * TSEQ + t) * GG + g] = p;
    Bv = nB; Cv = nC; dv = nd;
  }
}

// ---------------- gating: yg = sigmoid(u) * y_broadcast (bf16 out) ----------------
__global__ void gate_bf16(const __hip_bfloat16* __restrict__ uvb, const float* __restrict__ y,
                          __hip_bfloat16* __restrict__ yg) {
  size_t idx = (size_t)blockIdx.x * 256 + threadIdx.x;  // over BT*EDIM
  int bt = (int)(idx >> 11);
  int e = (int)(idx & (EDIM - 1));
  float u = __bfloat162float(uvb[(size_t)bt * E2 + e]);
  float yv = y[(size_t)bt * GG + (e >> 7)];
  yg[idx] = __float2bfloat16(yv / (1.f + expf(-u)));
}

// ---------------- swiglu: ffb = silu(t1)*t3 (bf16) ----------------
__global__ void swiglu_bf16(const __hip_bfloat16* __restrict__ t1,
                            const __hip_bfloat16* __restrict__ t3,
                            __hip_bfloat16* __restrict__ ffb) {
  size_t idx = (size_t)blockIdx.x * 256 + threadIdx.x;  // over BT*DFF
  float g = __bfloat162float(t1[idx]);
  float s = g / (1.f + expf(-g));
  ffb[idx] = __float2bfloat16(s * __bfloat162float(t3[idx]));
}

extern "C" void kernel_launch(void* const* d_in, const int* in_sizes, int n_in,
                              void* d_out, int out_size, void* d_ws, size_t ws_size,
                              hipStream_t stream) {
  (void)in_sizes; (void)n_in; (void)out_size; (void)ws_size;
  const float* x         = (const float*)d_in[0];
  const float* norm1_w   = (const float*)d_in[1];
  const float* in_proj_w = (const float*)d_in[2];
  const float* conv_w    = (const float*)d_in[3];
  const float* B_proj_w  = (const float*)d_in[4];
  const float* C_proj_w  = (const float*)d_in[5];
  const float* dt_proj_w = (const float*)d_in[6];
  const float* dt_proj_b = (const float*)d_in[7];
  const float* A_log     = (const float*)d_in[8];
  const float* out_proj_w= (const float*)d_in[9];
  const float* norm2_w   = (const float*)d_in[10];
  const float* w1        = (const float*)d_in[11];
  const float* w2        = (const float*)d_in[12];
  const float* w3        = (const float*)d_in[13];
  float* out = (float*)d_out;

  char* ws = (char*)d_ws;
  const size_t MB = 1024 * 1024;
  __hip_bfloat16* uvb = (__hip_bfloat16*)(ws + 0);        // [4096,4096] 32MB; later t1b
  __hip_bfloat16* t3b = (__hip_bfloat16*)(ws + 32 * MB);  // [4096,4096] 32MB
  __hip_bfloat16* vb  = (__hip_bfloat16*)(ws + 64 * MB);  // [4096,2048] 16MB
  __hip_bfloat16* yg  = (__hip_bfloat16*)(ws + 80 * MB);  // [4096,2048] 16MB
  __hip_bfloat16* ffb = vb;                               // 32MB overlay (vb+yg dead)
  __hip_bfloat16* hb  = (__hip_bfloat16*)(ws + 96 * MB);  // [4096,1024] 8MB
  float* BCb  = (float*)(ws + 104 * MB);                  // [4096,512] 8MB
  float* dtb  = (float*)(ws + 112 * MB);                  // 256KB
  float* yb   = (float*)(ws + 112 * MB + 256 * 1024);     // 256KB
  float* Pc   = (float*)(ws + 113 * MB);                  // 128KB
  float* Sc   = (float*)(ws + 113 * MB + 128 * 1024);     // 128KB
  float* Init = (float*)(ws + 113 * MB + 256 * 1024);     // 128KB
  __hip_bfloat16* inT = (__hip_bfloat16*)(ws + 114 * MB); // [4096,1024] 8MB
  __hip_bfloat16* BCT = (__hip_bfloat16*)(ws + 122 * MB); // [512,2048] 2MB
  __hip_bfloat16* opT = (__hip_bfloat16*)(ws + 124 * MB); // [1024,2048] 4MB
  __hip_bfloat16* w1T = (__hip_bfloat16*)(ws + 128 * MB); // [4096,1024] 8MB
  __hip_bfloat16* w3T = (__hip_bfloat16*)(ws + 136 * MB); // 8MB
  __hip_bfloat16* w2T = (__hip_bfloat16*)(ws + 144 * MB); // [1024,4096] 8MB

  // 0) weight transpose+convert (W[K,N] -> WT[N,K] bf16)
  transpose_to_bf16<<<dim3(4096 / 32, 1024 / 32), 256, 0, stream>>>(in_proj_w, inT, 1024, 4096);
  transpose_to_bf16<<<dim3(256 / 32, 2048 / 32), 256, 0, stream>>>(B_proj_w, BCT, 2048, 256);
  transpose_to_bf16<<<dim3(256 / 32, 2048 / 32), 256, 0, stream>>>(C_proj_w, BCT + 256 * 2048, 2048, 256);
  transpose_to_bf16<<<dim3(1024 / 32, 2048 / 32), 256, 0, stream>>>(out_proj_w, opT, 2048, 1024);
  transpose_to_bf16<<<dim3(4096 / 32, 1024 / 32), 256, 0, stream>>>(w1, w1T, 1024, 4096);
  transpose_to_bf16<<<dim3(4096 / 32, 1024 / 32), 256, 0, stream>>>(w3, w3T, 1024, 4096);
  transpose_to_bf16<<<dim3(1024 / 32, 4096 / 32), 256, 0, stream>>>(w2, w2T, 4096, 1024);

  // 1) hb = rmsnorm(x) in bf16
  rmsnorm_bf16<<<BT, 256, 0, stream>>>(x, norm1_w, hb);
  // 2) uvb = hb @ in_proj  [4096,4096] bf16   (nbx=32, 1024 blocks)
  gemm_mfma<1><<<1024, 256, 0, stream>>>(hb, inT, nullptr, uvb, BT, E2, DMODEL, 32);
  // 3) vb = causal dwconv(uvb[:, E:2E])
  dwconv_bf16<<<dim3(EDIM / 256, BT), 256, 0, stream>>>(uvb, conv_w, vb);
  // 4) BCb = vb @ [B_proj|C_proj]  (N=512, nbx=4, 128 blocks)
  gemm_mfma<0><<<128, 256, 0, stream>>>(vb, BCT, nullptr, BCb, BT, 512, EDIM, 4);
  // 5) dtb = softplus(vb @ dt_proj + b)
  dtproj_kernel<<<BT, 256, 0, stream>>>(vb, dt_proj_w, dt_proj_b, dtb);
  // 6) chunked scan -> yb [BT, G]
  scan_phase1<<<NCH, 512, 0, stream>>>(BCb, dtb, A_log, Pc, Sc);
  scan_phase2<<<1, 512, 0, stream>>>(Pc, Sc, Init);
  scan_phase3<<<NCH, 512, 0, stream>>>(BCb, dtb, A_log, Init, yb);
  // 7) yg = sigmoid(u) * broadcast(y)
  gate_bf16<<<(BT * EDIM) / 256, 256, 0, stream>>>(uvb, yb, yg);
  // 8) out = yg @ out_proj + x   (nbx=8, 256 blocks)
  gemm_mfma<0><<<256, 256, 0, stream>>>(yg, opT, x, out, BT, DMODEL, EDIM, 8);
  // 9) hb = rmsnorm(out)
  rmsnorm_bf16<<<BT, 256, 0, stream>>>(out, norm2_w, hb);
  // 10) t1b(=uvb) = hb @ w1 ; t3b = hb @ w3 (bf16, nbx=32)
  gemm_mfma<1><<<1024, 256, 0, stream>>>(hb, w1T, nullptr, uvb, BT, DFF, DMODEL, 32);
  gemm_mfma<1><<<1024, 256, 0, stream>>>(hb, w3T, nullptr, t3b, BT, DFF, DMODEL, 32);
  // 11) ffb = silu(t1)*t3 (bf16, overlays vb/yg)
  swiglu_bf16<<<(BT * DFF) / 256, 256, 0, stream>>>(uvb, t3b, ffb);
  // 12) out += ffb @ w2   (nbx=8, 256 blocks)
  gemm_mfma<0><<<256, 256, 0, stream>>>(ffb, w2T, out, out, BT, DMODEL, DFF, 8);
}

// Round 4
// 485.136 us; speedup vs baseline: 7.1107x; 1.1087x over previous
//
#include <hip/hip_runtime.h>
#include <hip/hip_bf16.h>
#include <math.h>

// Problem dims (fixed)
#define BT    4096     // B*T rows
#define TSEQ  2048
#define DMODEL 1024
#define EDIM  2048
#define E2    4096     // 2*E
#define GG    16       // groups
#define NS    16       // state
#define DFF   4096
#define NCH   64       // scan chunks
#define CL    32       // chunk length (NCH*CL == TSEQ)

typedef __attribute__((ext_vector_type(8))) short short8_t;
typedef __attribute__((ext_vector_type(4))) float f32x4;

__device__ __forceinline__ void gload_lds16(const void* g, void* l) {
  __builtin_amdgcn_global_load_lds((const __attribute__((address_space(1))) void*)g,
                                   (__attribute__((address_space(3))) void*)l, 16, 0, 0);
}

// ---------------- RMSNorm (fp32 in -> bf16 out) ----------------
__global__ void rmsnorm_bf16(const float* __restrict__ x, const float* __restrict__ w,
                             __hip_bfloat16* __restrict__ out) {
  int row = blockIdx.x;
  const float* xr = x + (size_t)row * DMODEL;
  float ss = 0.f;
#pragma unroll
  for (int i = 0; i < 4; ++i) {
    float v = xr[threadIdx.x + i * 256];
    ss += v * v;
  }
#pragma unroll
  for (int off = 32; off; off >>= 1) ss += __shfl_down(ss, off, 64);
  __shared__ float wsum[4];
  int lane = threadIdx.x & 63, wid = threadIdx.x >> 6;
  if (lane == 0) wsum[wid] = ss;
  __syncthreads();
  __shared__ float s_rms;
  if (threadIdx.x == 0)
    s_rms = rsqrtf((wsum[0] + wsum[1] + wsum[2] + wsum[3]) * (1.0f / DMODEL) + 1e-6f);
  __syncthreads();
  float rms = s_rms;
  __hip_bfloat16* orow = out + (size_t)row * DMODEL;
#pragma unroll
  for (int i = 0; i < 4; ++i) {
    int c = threadIdx.x + i * 256;
    orow[c] = __float2bfloat16(xr[c] * rms * w[c]);
  }
}

// ---------------- transpose + fp32->bf16 convert: W[K,N] -> WT[N,K] ----------------
__global__ void transpose_to_bf16(const float* __restrict__ W, __hip_bfloat16* __restrict__ WT,
                                  int K, int N) {
  __shared__ float tile[32][33];
  int tx = threadIdx.x & 31, ty = threadIdx.x >> 5;  // 32 x 8
  int n0 = blockIdx.x * 32, k0 = blockIdx.y * 32;
#pragma unroll
  for (int i = 0; i < 4; ++i)
    tile[ty + i * 8][tx] = W[(size_t)(k0 + ty + i * 8) * N + n0 + tx];
  __syncthreads();
#pragma unroll
  for (int i = 0; i < 4; ++i)
    WT[(size_t)(n0 + ty + i * 8) * K + k0 + tx] = __float2bfloat16(tile[tx][ty + i * 8]);
}

// ---------------- bf16 MFMA GEMM, dbuf 2-phase + T2 swizzle ----------------
// C[M,N] = A[M,K] @ WT[N,K]^T (+res). 128x128 tile, BK=64, 4 waves 2x2,
// 4x4 fragments of 16x16x32. 1D grid with XCD swizzle (gridDim.x % 8 == 0).
// LDS bank-conflict fix (T2, rule #21): global_load_lds writes LDS linearly,
// so the per-lane GLOBAL source col-byte is XOR-swizzled (cb ^ (row&7)<<4,
// involution within each 128B row window) and ds_read applies the same XOR.
template <int OUT_BF16>
__global__ __launch_bounds__(256) void gemm_mfma(
    const __hip_bfloat16* __restrict__ A, const __hip_bfloat16* __restrict__ WT,
    const float* __restrict__ res, void* __restrict__ Cout,
    int M, int N, int K, int nbx) {
  __shared__ __hip_bfloat16 As[2][128][64];
  __shared__ __hip_bfloat16 Bs[2][128][64];
  int tid = threadIdx.x;
  int lane = tid & 63, wid = tid >> 6;
  int wr = wid >> 1, wc = wid & 1;

  // XCD-aware swizzle (nwg multiple of 8)
  int nwg = gridDim.x;
  int q = nwg >> 3;
  int sw8 = (blockIdx.x & 7) * q + (blockIdx.x >> 3);
  int bx = sw8 % nbx, by = sw8 / nbx;
  int brow = by * 128, bcol = bx * 128;
  int lr = lane & 15, lq = lane >> 4;
  int sw = (lr & 7) << 4;   // read-side XOR (row&7 == lr&7 for all fragments)

  f32x4 acc[4][4];
#pragma unroll
  for (int m = 0; m < 4; ++m)
#pragma unroll
    for (int n = 0; n < 4; ++n) acc[m][n] = (f32x4){0.f, 0.f, 0.f, 0.f};

  const char* Ab = (const char*)(A + (size_t)brow * K);
  const char* Bb = (const char*)(WT + (size_t)bcol * K);
  const size_t rowBytes = (size_t)K * 2;

  // stage one K-tile (t) into buffer buf; global source pre-swizzled
  auto stage = [&](int buf, int t) {
    const size_t kb = (size_t)t * 128;  // t*64 cols * 2B
    char* asBase = (char*)&As[buf][0][0];
    char* bsBase = (char*)&Bs[buf][0][0];
#pragma unroll
    for (int i = 0; i < 4; ++i) {
      int blk = i * 4 + wid;
      int o16 = (blk << 6) + lane;
      int r = o16 >> 3;
      int cb = ((o16 & 7) << 4) ^ ((r & 7) << 4);  // inverse-swizzled source col
      gload_lds16(Ab + (size_t)r * rowBytes + kb + cb, asBase + (blk << 10));
    }
#pragma unroll
    for (int i = 0; i < 4; ++i) {
      int blk = i * 4 + wid;
      int o16 = (blk << 6) + lane;
      int r = o16 >> 3;
      int cb = ((o16 & 7) << 4) ^ ((r & 7) << 4);
      gload_lds16(Bb + (size_t)r * rowBytes + kb + cb, bsBase + (blk << 10));
    }
  };

  const int nt = K >> 6;
  stage(0, 0);
  __syncthreads();  // drains vmcnt, all waves see tile 0

  int cur = 0;
  for (int t = 0; t < nt; ++t) {
    if (t + 1 < nt) stage(cur ^ 1, t + 1);  // issue next-tile loads first
#pragma unroll
    for (int kk6 = 0; kk6 < 2; ++kk6) {
      int cbs = ((kk6 << 6) + (lq << 4)) ^ sw;   // swizzled byte col
      short8_t a[4], b[4];
#pragma unroll
      for (int m = 0; m < 4; ++m)
        a[m] = *(const short8_t*)((const char*)&As[cur][wr * 64 + m * 16 + lr][0] + cbs);
#pragma unroll
      for (int n = 0; n < 4; ++n)
        b[n] = *(const short8_t*)((const char*)&Bs[cur][wc * 64 + n * 16 + lr][0] + cbs);
#pragma unroll
      for (int m = 0; m < 4; ++m)
#pragma unroll
        for (int n = 0; n < 4; ++n)
          acc[m][n] = __builtin_amdgcn_mfma_f32_16x16x32_bf16(a[m], b[n], acc[m][n], 0, 0, 0);
    }
    __syncthreads();  // drains staged loads (vmcnt 0) + barrier
    cur ^= 1;
  }

  // epilogue: C/D layout col=lane&15, row=(lane>>4)*4+reg
#pragma unroll
  for (int m = 0; m < 4; ++m) {
    int row0 = brow + wr * 64 + m * 16 + (lane >> 4) * 4;
#pragma unroll
    for (int n = 0; n < 4; ++n) {
      int col = bcol + wc * 64 + n * 16 + lr;
#pragma unroll
      for (int j = 0; j < 4; ++j) {
        size_t idx = (size_t)(row0 + j) * N + col;
        float o = acc[m][n][j];
        if (res) o += res[idx];
        if constexpr (OUT_BF16)
          ((__hip_bfloat16*)Cout)[idx] = __float2bfloat16(o);
        else
          ((float*)Cout)[idx] = o;
      }
    }
  }
}

// ---------------- depthwise causal conv (K=7), bf16 in/out ----------------
__global__ void dwconv_bf16(const __hip_bfloat16* __restrict__ uvb, const float* __restrict__ cw,
                            __hip_bfloat16* __restrict__ vout) {
  int e = blockIdx.x * 256 + threadIdx.x;   // 0..2047
  int bt = blockIdx.y;                       // 0..4095
  int t = bt & (TSEQ - 1);
  float w[7];
#pragma unroll
  for (int k = 0; k < 7; ++k) w[k] = cw[e * 7 + k];
  const __hip_bfloat16* col = uvb + (size_t)bt * E2 + EDIM + e;  // v half
  float acc = 0.f;
#pragma unroll
  for (int k = 0; k < 7; ++k) {
    int ts = t - 6 + k;
    if (ts >= 0) acc += w[k] * __bfloat162float(col[(ts - t) * (int)E2]);
  }
  vout[(size_t)bt * EDIM + e] = __float2bfloat16(acc);
}

// ---------------- dt projection + softplus (bf16 v, fp32 weights) ----------------
__global__ void dtproj_kernel(const __hip_bfloat16* __restrict__ v, const float* __restrict__ w,
                              const float* __restrict__ bias, float* __restrict__ dtout) {
  int row = blockIdx.x;
  const __hip_bfloat16* vr = v + (size_t)row * EDIM;
  float acc[GG] = {};
  for (int e = threadIdx.x; e < EDIM; e += 256) {
    float vv = __bfloat162float(vr[e]);
    const float* wr = w + (size_t)e * GG;
#pragma unroll
    for (int g = 0; g < GG; ++g) acc[g] = fmaf(vv, wr[g], acc[g]);
  }
#pragma unroll
  for (int g = 0; g < GG; ++g)
#pragma unroll
    for (int off = 32; off; off >>= 1) acc[g] += __shfl_down(acc[g], off, 64);
  __shared__ float red[4][GG];
  int lane = threadIdx.x & 63, wid = threadIdx.x >> 6;
  if (lane == 0) {
#pragma unroll
    for (int g = 0; g < GG; ++g) red[wid][g] = acc[g];
  }
  __syncthreads();
  if (threadIdx.x < GG) {
    float s = red[0][threadIdx.x] + red[1][threadIdx.x] + red[2][threadIdx.x] +
              red[3][threadIdx.x] + bias[threadIdx.x];
    dtout[(size_t)row * GG + threadIdx.x] = (s > 20.f) ? s : log1pf(expf(s));
  }
}

// ---------------- chunked selective scan (BC fused: [BT,512], Ct at +256) ----------------
__global__ void scan_phase1(const float* __restrict__ BC, const float* __restrict__ dt,
                            const float* __restrict__ A_log,
                            float* __restrict__ Pc, float* __restrict__ Sc) {
  int c = blockIdx.x, tid = threadIdx.x;
  int b = tid >> 8, g = (tid >> 4) & 15, n = tid & 15;
  float A = -expf(A_log[g * NS + n]);
  int t0 = c * CL;
  size_t bOff = (size_t)b * TSEQ * 512 + g * 16 + n;
  size_t dOff = (size_t)b * TSEQ * GG + g;
  float P = 1.f, S = 0.f;
  float Bv = BC[bOff + (size_t)t0 * 512], dv = dt[dOff + (size_t)t0 * GG];
  for (int t = t0; t < t0 + CL; ++t) {
    float nB = 0.f, nd = 0.f;
    if (t + 1 < t0 + CL) {
      nB = BC[bOff + (size_t)(t + 1) * 512];
      nd = dt[dOff + (size_t)(t + 1) * GG];
    }
    float a = expf(dv * A);
    S = a * S + dv * Bv;
    P *= a;
    Bv = nB; dv = nd;
  }
  Pc[c * 512 + tid] = P;
  Sc[c * 512 + tid] = S;
}

__global__ void scan_phase2(const float* __restrict__ Pc, const float* __restrict__ Sc,
                            float* __restrict__ Init) {
  int tid = threadIdx.x;
  float s = 0.f;
  for (int c = 0; c < NCH; ++c) {
    Init[c * 512 + tid] = s;
    s = Pc[c * 512 + tid] * s + Sc[c * 512 + tid];
  }
}

__global__ void scan_phase3(const float* __restrict__ BC, const float* __restrict__ dt,
                            const float* __restrict__ A_log, const float* __restrict__ Init,
                            float* __restrict__ y) {
  int c = blockIdx.x, tid = threadIdx.x;
  int b = tid >> 8, g = (tid >> 4) & 15, n = tid & 15;
  float A = -expf(A_log[g * NS + n]);
  int t0 = c * CL;
  size_t bOff = (size_t)b * TSEQ * 512 + g * 16 + n;
  size_t dOff = (size_t)b * TSEQ * GG + g;
  float state = Init[c * 512 + tid];
  float Bv = BC[bOff + (size_t)t0 * 512], Cv = BC[bOff + 256 + (size_t)t0 * 512],
        dv = dt[dOff + (size_t)t0 * GG];
  for (int t = t0; t < t0 + CL; ++t) {
    float nB = 0.f, nC = 0.f, nd = 0.f;
    if (t + 1 < t0 + CL) {
      size_t r = bOff + (size_t)(t + 1) * 512;
      nB = BC[r]; nC = BC[r + 256];
      nd = dt[dOff + (size_t)(t + 1) * GG];
    }
    float a = expf(dv * A);
    state = a * state + dv * Bv;
    float p = state * Cv;
#pragma unroll
    for (int off = 8; off; off >>= 1) p += __shfl_down(p, off, 16);
    if (n == 0) y[(size_t)(b * TSEQ + t) * GG + g] = p;
    Bv = nB; Cv = nC; dv = nd;
  }
}

// ---------------- gating: yg = sigmoid(u) * y_broadcast (bf16 out) ----------------
__global__ void gate_bf16(const __hip_bfloat16* __restrict__ uvb, const float* __restrict__ y,
                          __hip_bfloat16* __restrict__ yg) {
  size_t idx = (size_t)blockIdx.x * 256 + threadIdx.x;  // over BT*EDIM
  int bt = (int)(idx >> 11);
  int e = (int)(idx & (EDIM - 1));
  float u = __bfloat162float(uvb[(size_t)bt * E2 + e]);
  float yv = y[(size_t)bt * GG + (e >> 7)];
  yg[idx] = __float2bfloat16(yv / (1.f + expf(-u)));
}

// ---------------- swiglu on fused [t1|t3] buffer: ffb = silu(t1)*t3 ----------------
__global__ void swiglu_fused(const __hip_bfloat16* __restrict__ uv3,
                             __hip_bfloat16* __restrict__ ffb) {
  size_t idx = (size_t)blockIdx.x * 256 + threadIdx.x;  // over BT*DFF
  int bt = (int)(idx >> 12);
  int j = (int)(idx & (DFF - 1));
  const __hip_bfloat16* row = uv3 + (size_t)bt * 8192;
  float g = __bfloat162float(row[j]);
  float s = g / (1.f + expf(-g));
  ffb[idx] = __float2bfloat16(s * __bfloat162float(row[DFF + j]));
}

extern "C" void kernel_launch(void* const* d_in, const int* in_sizes, int n_in,
                              void* d_out, int out_size, void* d_ws, size_t ws_size,
                              hipStream_t stream) {
  (void)in_sizes; (void)n_in; (void)out_size; (void)ws_size;
  const float* x         = (const float*)d_in[0];
  const float* norm1_w   = (const float*)d_in[1];
  const float* in_proj_w = (const float*)d_in[2];
  const float* conv_w    = (const float*)d_in[3];
  const float* B_proj_w  = (const float*)d_in[4];
  const float* C_proj_w  = (const float*)d_in[5];
  const float* dt_proj_w = (const float*)d_in[6];
  const float* dt_proj_b = (const float*)d_in[7];
  const float* A_log     = (const float*)d_in[8];
  const float* out_proj_w= (const float*)d_in[9];
  const float* norm2_w   = (const float*)d_in[10];
  const float* w1        = (const float*)d_in[11];
  const float* w2        = (const float*)d_in[12];
  const float* w3        = (const float*)d_in[13];
  float* out = (float*)d_out;

  char* ws = (char*)d_ws;
  const size_t MB = 1024 * 1024;
  __hip_bfloat16* uvb  = (__hip_bfloat16*)(ws + 0);        // [4096,4096] 32MB; later ffb
  __hip_bfloat16* uv3b = (__hip_bfloat16*)(ws + 32 * MB);  // [4096,8192] 64MB (w13 out)
  __hip_bfloat16* vb   = (__hip_bfloat16*)(ws + 64 * MB);  // [4096,2048] 16MB (dies before uv3b)
  __hip_bfloat16* yg   = (__hip_bfloat16*)(ws + 80 * MB);  // [4096,2048] 16MB (dies before uv3b)
  __hip_bfloat16* ffb  = uvb;                              // 32MB overlay (uvb dead after gate)
  __hip_bfloat16* hb   = (__hip_bfloat16*)(ws + 96 * MB);  // [4096,1024] 8MB
  float* BCb  = (float*)(ws + 104 * MB);                   // [4096,512] 8MB
  float* dtb  = (float*)(ws + 112 * MB);                   // 256KB
  float* yb   = (float*)(ws + 112 * MB + 256 * 1024);      // 256KB
  float* Pc   = (float*)(ws + 113 * MB);                   // 128KB
  float* Sc   = (float*)(ws + 113 * MB + 128 * 1024);      // 128KB
  float* Init = (float*)(ws + 113 * MB + 256 * 1024);      // 128KB
  __hip_bfloat16* inT  = (__hip_bfloat16*)(ws + 114 * MB); // [4096,1024] 8MB
  __hip_bfloat16* BCT  = (__hip_bfloat16*)(ws + 122 * MB); // [512,2048] 2MB
  __hip_bfloat16* opT  = (__hip_bfloat16*)(ws + 124 * MB); // [1024,2048] 4MB
  __hip_bfloat16* w13T = (__hip_bfloat16*)(ws + 128 * MB); // [8192,1024] 16MB
  __hip_bfloat16* w2T  = (__hip_bfloat16*)(ws + 144 * MB); // [1024,4096] 8MB

  // 0) weight transpose+convert (W[K,N] -> WT[N,K] bf16)
  transpose_to_bf16<<<dim3(4096 / 32, 1024 / 32), 256, 0, stream>>>(in_proj_w, inT, 1024, 4096);
  transpose_to_bf16<<<dim3(256 / 32, 2048 / 32), 256, 0, stream>>>(B_proj_w, BCT, 2048, 256);
  transpose_to_bf16<<<dim3(256 / 32, 2048 / 32), 256, 0, stream>>>(C_proj_w, BCT + 256 * 2048, 2048, 256);
  transpose_to_bf16<<<dim3(1024 / 32, 2048 / 32), 256, 0, stream>>>(out_proj_w, opT, 2048, 1024);
  transpose_to_bf16<<<dim3(4096 / 32, 1024 / 32), 256, 0, stream>>>(w1, w13T, 1024, 4096);
  transpose_to_bf16<<<dim3(4096 / 32, 1024 / 32), 256, 0, stream>>>(w3, w13T + (size_t)4096 * 1024, 1024, 4096);
  transpose_to_bf16<<<dim3(1024 / 32, 4096 / 32), 256, 0, stream>>>(w2, w2T, 4096, 1024);

  // 1) hb = rmsnorm(x) in bf16
  rmsnorm_bf16<<<BT, 256, 0, stream>>>(x, norm1_w, hb);
  // 2) uvb = hb @ in_proj  [4096,4096] bf16   (nbx=32, 1024 blocks)
  gemm_mfma<1><<<1024, 256, 0, stream>>>(hb, inT, nullptr, uvb, BT, E2, DMODEL, 32);
  // 3) vb = causal dwconv(uvb[:, E:2E])
  dwconv_bf16<<<dim3(EDIM / 256, BT), 256, 0, stream>>>(uvb, conv_w, vb);
  // 4) BCb = vb @ [B_proj|C_proj]  (N=512, nbx=4, 128 blocks)
  gemm_mfma<0><<<128, 256, 0, stream>>>(vb, BCT, nullptr, BCb, BT, 512, EDIM, 4);
  // 5) dtb = softplus(vb @ dt_proj + b)
  dtproj_kernel<<<BT, 256, 0, stream>>>(vb, dt_proj_w, dt_proj_b, dtb);
  // 6) chunked scan -> yb [BT, G]
  scan_phase1<<<NCH, 512, 0, stream>>>(BCb, dtb, A_log, Pc, Sc);
  scan_phase2<<<1, 512, 0, stream>>>(Pc, Sc, Init);
  scan_phase3<<<NCH, 512, 0, stream>>>(BCb, dtb, A_log, Init, yb);
  // 7) yg = sigmoid(u) * broadcast(y)
  gate_bf16<<<(BT * EDIM) / 256, 256, 0, stream>>>(uvb, yb, yg);
  // 8) out = yg @ out_proj + x   (nbx=8, 256 blocks)
  gemm_mfma<0><<<256, 256, 0, stream>>>(yg, opT, x, out, BT, DMODEL, EDIM, 8);
  // 9) hb = rmsnorm(out)
  rmsnorm_bf16<<<BT, 256, 0, stream>>>(out, norm2_w, hb);
  // 10) uv3b = hb @ [w1|w3]  (N=8192, nbx=64, 2048 blocks)
  gemm_mfma<1><<<2048, 256, 0, stream>>>(hb, w13T, nullptr, uv3b, BT, 8192, DMODEL, 64);
  // 11) ffb = silu(t1)*t3 (bf16, overlays uvb)
  swiglu_fused<<<(BT * DFF) / 256, 256, 0, stream>>>(uv3b, ffb);
  // 12) out += ffb @ w2   (nbx=8, 256 blocks)
  gemm_mfma<0><<<256, 256, 0, stream>>>(ffb, w2T, out, out, BT, DMODEL, DFF, 8);
}